// Round 1
// baseline (2003.067 us; speedup 1.0000x reference)
//
#include <hip/hip_runtime.h>
#include <math.h>

#define NB 16
#define NN 2048
#define ND 256
#define BNtot (NB*NN)
#define HH 33554432u   // half of 16*2048*2048

// ---------------- threefry2x32 gumbel, bit-exact vs jax.random.key(42) ----------------
__device__ __forceinline__ float gumbelv(unsigned b, unsigned n, unsigned m){
  unsigned f = (b<<22) | (n<<11) | m;          // flat index into (16,2048,2048)
  unsigned x0 = (b < 8u) ? f : (f - HH);       // pair index
  unsigned x1 = x0 + HH;
  const unsigned ks0=0u, ks1=42u, ks2=0u^42u^0x1BD11BDAu;
  unsigned v0 = x0 + ks0;
  unsigned v1 = x1 + ks1;
#define TFR(r) { v0 += v1; v1 = (v1<<(r))|(v1>>(32-(r))); v1 ^= v0; }
  TFR(13) TFR(15) TFR(26) TFR(6)
  v0 += ks1; v1 += ks2 + 1u;
  TFR(17) TFR(29) TFR(16) TFR(24)
  v0 += ks2; v1 += ks0 + 2u;
  TFR(13) TFR(15) TFR(26) TFR(6)
  v0 += ks0; v1 += ks1 + 3u;
  TFR(17) TFR(29) TFR(16) TFR(24)
  v0 += ks1; v1 += ks2 + 4u;
  TFR(13) TFR(15) TFR(26) TFR(6)
  v0 += ks2; v1 += ks0 + 5u;
#undef TFR
  unsigned bits = (b < 8u) ? v0 : v1;          // out = concat(r0, r1)
  float fl = __uint_as_float((bits>>9) | 0x3F800000u) - 1.0f;  // [0,1)
  // u = max(minval, fl*(maxval-minval)+minval); (1.0f-1e-10f)==1.0f in fp32
  float u = fmaxf(1e-10f, fl + 1e-10f);
  return -logf(-logf(u));
}

// ---------------- row norms ----------------
__global__ void knorms(const float* __restrict__ LLF, const float* __restrict__ HLF,
                       float* __restrict__ nl, float* __restrict__ nh){
  int row = blockIdx.x;                 // 0..BNtot-1
  int wave = threadIdx.x >> 6;          // 0: LLF, 1: HLF
  int lane = threadIdx.x & 63;
  const float* src = wave ? HLF : LLF;
  float4 v = ((const float4*)(src + (size_t)row*ND))[lane];
  float s = v.x*v.x + v.y*v.y + v.z*v.z + v.w*v.w;
  for (int o=32;o;o>>=1) s += __shfl_down(s,o);
  if (lane==0) (wave? nh: nl)[row] = sqrtf(s);
}

// ---------------- pass A: column softmax stats (M, 1/S) ----------------
__launch_bounds__(256)
__global__ void kstats(const float* __restrict__ A, const float* __restrict__ Bm,
                       const float* __restrict__ nl, const float* __restrict__ nh,
                       float* __restrict__ Mout, float* __restrict__ Sinv){
  __shared__ float As[64][33];
  __shared__ float Bs[64][33];
  __shared__ float Cs[64][65];
  const int b  = blockIdx.x >> 5;
  const int m0 = (blockIdx.x & 31) << 6;
  const float* Ab = A  + (size_t)b*NN*ND;
  const float* Bb = Bm + (size_t)b*NN*ND;
  const int tid = threadIdx.x;
  const int tx = tid & 15, ty = tid >> 4;
  float nhv[4];
  #pragma unroll
  for (int j=0;j<4;j++) nhv[j] = nh[b*NN + m0 + tx*4 + j];
  float Mr = -INFINITY, Sr = 0.0f;   // meaningful for tid<64

  for (int nt=0; nt<NN; nt+=64){
    float acc[4][4] = {{0.f,0.f,0.f,0.f},{0.f,0.f,0.f,0.f},{0.f,0.f,0.f,0.f},{0.f,0.f,0.f,0.f}};
    for (int kc=0; kc<ND; kc+=32){
      __syncthreads();
      #pragma unroll
      for (int s=0;s<2;s++){
        int f = tid + (s<<8);
        int r = f >> 3;
        int c = (f & 7) << 2;
        float4 va = *(const float4*)(Ab + (size_t)(nt+r)*ND + kc + c);
        As[r][c]=va.x; As[r][c+1]=va.y; As[r][c+2]=va.z; As[r][c+3]=va.w;
        float4 vb = *(const float4*)(Bb + (size_t)(m0+r)*ND + kc + c);
        Bs[r][c]=vb.x; Bs[r][c+1]=vb.y; Bs[r][c+2]=vb.z; Bs[r][c+3]=vb.w;
      }
      __syncthreads();
      #pragma unroll 4
      for (int k=0;k<32;k++){
        float a0=As[ty*4+0][k], a1=As[ty*4+1][k], a2=As[ty*4+2][k], a3=As[ty*4+3][k];
        float b0=Bs[tx*4+0][k], b1=Bs[tx*4+1][k], b2=Bs[tx*4+2][k], b3=Bs[tx*4+3][k];
        acc[0][0]+=a0*b0; acc[0][1]+=a0*b1; acc[0][2]+=a0*b2; acc[0][3]+=a0*b3;
        acc[1][0]+=a1*b0; acc[1][1]+=a1*b1; acc[1][2]+=a1*b2; acc[1][3]+=a1*b3;
        acc[2][0]+=a2*b0; acc[2][1]+=a2*b1; acc[2][2]+=a2*b2; acc[2][3]+=a2*b3;
        acc[3][0]+=a3*b0; acc[3][1]+=a3*b1; acc[3][2]+=a3*b2; acc[3][3]+=a3*b3;
      }
    }
    float nlv[4];
    #pragma unroll
    for (int i=0;i<4;i++) nlv[i] = nl[b*NN + nt + ty*4 + i];
    __syncthreads();   // previous tile's column-phase reads of Cs done
    #pragma unroll
    for (int i=0;i<4;i++)
      #pragma unroll
      for (int j=0;j<4;j++){
        float denom = fmaxf(nlv[i]*nhv[j], 1e-8f);
        Cs[ty*4+i][tx*4+j] = (acc[i][j]/denom)*0.0625f;   // /sqrt(256)
      }
    __syncthreads();
    if (tid < 64){
      float tmax = -INFINITY;
      #pragma unroll 8
      for (int r=0;r<64;r++) tmax = fmaxf(tmax, Cs[r][tid]);
      float newM = fmaxf(Mr, tmax);
      float s = 0.0f;
      #pragma unroll 4
      for (int r=0;r<64;r++) s += expf(Cs[r][tid]-newM);
      Sr = Sr*expf(Mr-newM) + s;
      Mr = newM;
    }
  }
  if (tid < 64){
    Mout[b*NN+m0+tid] = Mr;
    Sinv[b*NN+m0+tid] = 1.0f/Sr;
  }
}

// ---------------- pass B: argmax_n(probs + gumbel) ----------------
__launch_bounds__(256)
__global__ void kargmax(const float* __restrict__ A, const float* __restrict__ Bm,
                        const float* __restrict__ nl, const float* __restrict__ nh,
                        const float* __restrict__ Mv, const float* __restrict__ Sv,
                        int* __restrict__ idxout){
  __shared__ float As[64][33];
  __shared__ float Bs[64][33];
  __shared__ float Vs[16][64];
  __shared__ int   Is[16][64];
  const int b  = blockIdx.x >> 5;
  const int m0 = (blockIdx.x & 31) << 6;
  const float* Ab = A  + (size_t)b*NN*ND;
  const float* Bb = Bm + (size_t)b*NN*ND;
  const int tid = threadIdx.x;
  const int tx = tid & 15, ty = tid >> 4;
  float nhv[4], Mj[4], iSj[4];
  #pragma unroll
  for (int j=0;j<4;j++){
    int m = m0 + tx*4 + j;
    nhv[j] = nh[b*NN + m];
    Mj[j]  = Mv[b*NN + m];
    iSj[j] = Sv[b*NN + m];
  }
  float bestV = -INFINITY; int bestN = 0;   // for tid<64

  for (int nt=0; nt<NN; nt+=64){
    float acc[4][4] = {{0.f,0.f,0.f,0.f},{0.f,0.f,0.f,0.f},{0.f,0.f,0.f,0.f},{0.f,0.f,0.f,0.f}};
    for (int kc=0; kc<ND; kc+=32){
      __syncthreads();
      #pragma unroll
      for (int s=0;s<2;s++){
        int f = tid + (s<<8);
        int r = f >> 3;
        int c = (f & 7) << 2;
        float4 va = *(const float4*)(Ab + (size_t)(nt+r)*ND + kc + c);
        As[r][c]=va.x; As[r][c+1]=va.y; As[r][c+2]=va.z; As[r][c+3]=va.w;
        float4 vb = *(const float4*)(Bb + (size_t)(m0+r)*ND + kc + c);
        Bs[r][c]=vb.x; Bs[r][c+1]=vb.y; Bs[r][c+2]=vb.z; Bs[r][c+3]=vb.w;
      }
      __syncthreads();
      #pragma unroll 4
      for (int k=0;k<32;k++){
        float a0=As[ty*4+0][k], a1=As[ty*4+1][k], a2=As[ty*4+2][k], a3=As[ty*4+3][k];
        float b0=Bs[tx*4+0][k], b1=Bs[tx*4+1][k], b2=Bs[tx*4+2][k], b3=Bs[tx*4+3][k];
        acc[0][0]+=a0*b0; acc[0][1]+=a0*b1; acc[0][2]+=a0*b2; acc[0][3]+=a0*b3;
        acc[1][0]+=a1*b0; acc[1][1]+=a1*b1; acc[1][2]+=a1*b2; acc[1][3]+=a1*b3;
        acc[2][0]+=a2*b0; acc[2][1]+=a2*b1; acc[2][2]+=a2*b2; acc[2][3]+=a2*b3;
        acc[3][0]+=a3*b0; acc[3][1]+=a3*b1; acc[3][2]+=a3*b2; acc[3][3]+=a3*b3;
      }
    }
    float nlv[4];
    #pragma unroll
    for (int i=0;i<4;i++) nlv[i] = nl[b*NN + nt + ty*4 + i];
    float lv[4]; int li[4];
    #pragma unroll
    for (int j=0;j<4;j++){ lv[j] = -INFINITY; li[j] = 0; }
    #pragma unroll
    for (int i=0;i<4;i++){
      int n = nt + ty*4 + i;
      #pragma unroll
      for (int j=0;j<4;j++){
        float denom = fmaxf(nlv[i]*nhv[j], 1e-8f);
        float sim = (acc[i][j]/denom)*0.0625f;
        float p = expf(sim - Mj[j]) * iSj[j];
        float v = p + gumbelv((unsigned)b, (unsigned)n, (unsigned)(m0 + tx*4 + j));
        if (v > lv[j]) { lv[j] = v; li[j] = n; }   // ascending n => first-max
      }
    }
    __syncthreads();   // previous tile's Vs/Is reads done
    #pragma unroll
    for (int j=0;j<4;j++){ Vs[ty][tx*4+j]=lv[j]; Is[ty][tx*4+j]=li[j]; }
    __syncthreads();
    if (tid < 64){
      #pragma unroll 4
      for (int t=0;t<16;t++){                      // ascending ty => ascending n
        float v = Vs[t][tid];
        if (v > bestV){ bestV = v; bestN = Is[t][tid]; }
      }
    }
  }
  if (tid < 64) idxout[b*NN + m0 + tid] = bestN;
}

// ---------------- per-batch counting sort of idx ----------------
__global__ void ksort(const int* __restrict__ idx, int* __restrict__ cntg,
                      int* __restrict__ offg, int* __restrict__ sl){
  __shared__ int c[NN];
  __shared__ int part[256];
  int b = blockIdx.x, tid = threadIdx.x;
  for (int v=tid; v<NN; v+=256) c[v]=0;
  __syncthreads();
  for (int j=tid; j<NN; j+=256) atomicAdd(&c[idx[b*NN+j]], 1);
  __syncthreads();
  int base = tid*8, s=0, lc[8];
  #pragma unroll
  for (int k=0;k<8;k++){ lc[k]=c[base+k]; s+=lc[k]; }
  part[tid]=s; __syncthreads();
  for (int o=1;o<256;o<<=1){            // Hillis-Steele inclusive scan
    int v = (tid>=o)? part[tid-o] : 0;
    __syncthreads();
    part[tid]+=v;
    __syncthreads();
  }
  int run = part[tid]-s;                // exclusive prefix
  #pragma unroll
  for (int k=0;k<8;k++){
    int v = base+k;
    cntg[b*NN+v]=lc[k];
    offg[b*NN+v]=run;
    for (int j=0;j<lc[k];j++) sl[b*NN+run+j]=v;
    run += lc[k];
  }
}

// ---------------- w = cos(aligned, LLF) ----------------
__global__ void kw(const float* __restrict__ LLF, const float* __restrict__ HLF,
                   const float* __restrict__ nl, const float* __restrict__ nh,
                   const int* __restrict__ sl, float* __restrict__ w){
  int g = blockIdx.x*4 + (threadIdx.x>>6);   // b*NN + i
  int lane = threadIdx.x & 63;
  int b = g >> 11;
  int s = sl[g];
  float4 a = ((const float4*)(HLF + ((size_t)b*NN + s)*ND))[lane];
  float4 l = ((const float4*)(LLF + (size_t)g*ND))[lane];
  float d = a.x*l.x + a.y*l.y + a.z*l.z + a.w*l.w;
  for (int o=32;o;o>>=1) d += __shfl_down(d,o);
  if (lane==0){
    float denom = fmaxf(nh[b*NN+s]*nl[g], 1e-8f);
    w[g] = d/denom;
  }
}

// ---------------- noise = softmax(w/0.1) per batch ----------------
__global__ void knoise(const float* __restrict__ w, float* __restrict__ nz){
  int b = blockIdx.x, tid = threadIdx.x;
  __shared__ float sred[4];
  float x[8]; float mx = -INFINITY;
  #pragma unroll
  for (int k=0;k<8;k++){ x[k] = w[b*NN + tid*8 + k] / 0.1f; mx = fmaxf(mx, x[k]); }
  for (int o=32;o;o>>=1) mx = fmaxf(mx, __shfl_down(mx,o));
  mx = __shfl(mx, 0);
  if ((tid&63)==0) sred[tid>>6] = mx;
  __syncthreads();
  mx = fmaxf(fmaxf(sred[0],sred[1]), fmaxf(sred[2],sred[3]));
  __syncthreads();
  float e[8]; float s = 0.f;
  #pragma unroll
  for (int k=0;k<8;k++){ e[k] = expf(x[k]-mx); s += e[k]; }
  for (int o=32;o;o>>=1) s += __shfl_down(s,o);
  s = __shfl(s, 0);
  if ((tid&63)==0) sred[tid>>6] = s;
  __syncthreads();
  s = sred[0]+sred[1]+sred[2]+sred[3];
  #pragma unroll
  for (int k=0;k<8;k++) nz[b*NN + tid*8 + k] = e[k]/s;
}

// ---------------- final assemble: numpy last-wins scatter ----------------
__global__ void kfinal(const float* __restrict__ LLF, const float* __restrict__ HLF,
                       const int* __restrict__ cnt, const int* __restrict__ off,
                       const float* __restrict__ nz, float* __restrict__ out){
  int row = blockIdx.x;              // b*NN + n
  int lane = threadIdx.x;            // 64
  int b = row >> 11;
  float4 h = ((const float4*)(HLF + (size_t)row*ND))[lane];
  int c = cnt[row];
  if (c > 0){
    int i = off[row] + c - 1;        // last duplicate wins (numpy semantics)
    float ns = nz[b*NN + i];
    float4 l = ((const float4*)(LLF + ((size_t)(b*NN + i))*ND))[lane];
    h.x += l.x*ns; h.y += l.y*ns; h.z += l.z*ns; h.w += l.w*ns;
  }
  ((float4*)(out + (size_t)row*ND))[lane] = h;
}

extern "C" void kernel_launch(void* const* d_in, const int* in_sizes, int n_in,
                              void* d_out, int out_size, void* d_ws, size_t ws_size,
                              hipStream_t stream){
  const float* LLF = (const float*)d_in[0];
  const float* HLF = (const float*)d_in[1];
  float* out = (float*)d_out;
  float* ws = (float*)d_ws;
  float* nl  = ws;
  float* nh  = ws + 1*BNtot;
  float* Mv  = ws + 2*BNtot;
  float* iS  = ws + 3*BNtot;
  int*   idx = (int*)(ws + 4*BNtot);
  int*   cnt = (int*)(ws + 5*BNtot);
  int*   off = (int*)(ws + 6*BNtot);
  int*   sl  = (int*)(ws + 7*BNtot);
  float* wv  = ws + 8*BNtot;
  float* nz  = ws + 9*BNtot;

  hipLaunchKernelGGL(knorms,  dim3(BNtot),   dim3(128), 0, stream, LLF, HLF, nl, nh);
  hipLaunchKernelGGL(kstats,  dim3(NB*32),   dim3(256), 0, stream, LLF, HLF, nl, nh, Mv, iS);
  hipLaunchKernelGGL(kargmax, dim3(NB*32),   dim3(256), 0, stream, LLF, HLF, nl, nh, Mv, iS, idx);
  hipLaunchKernelGGL(ksort,   dim3(NB),      dim3(256), 0, stream, idx, cnt, off, sl);
  hipLaunchKernelGGL(kw,      dim3(BNtot/4), dim3(256), 0, stream, LLF, HLF, nl, nh, sl, wv);
  hipLaunchKernelGGL(knoise,  dim3(NB),      dim3(256), 0, stream, wv, nz);
  hipLaunchKernelGGL(kfinal,  dim3(BNtot),   dim3(64),  0, stream, LLF, HLF, cnt, off, nz, out);
}